// Round 10
// baseline (311.065 us; speedup 1.0000x reference)
//
#include <hip/hip_runtime.h>
#include <hip/hip_bf16.h>

// QuantizedLinearINT4: out = x @ dequant(W).T + bias
// M=8192, N=OUT=4096, K=IN=4096.
// Round-10: de-synchronized co-residency. Two independent 4-wave blocks per
// CU (tile 256x128, 256 thr, LDS 72 KiB) so one block's dequant-VALU/staging
// overlaps the other's MFMA burst (cross-block m114 overlap; single-block
// barriers lockstep all waves into the same phase -> pipes never overlap).
// Numerics = round-9 (verified): B staged as packed nibbles, frag built as
// bf16(1+nib/16) via bit-ops, scale/zp folded into epilogue with rowsum.

typedef __bf16 bf16;
typedef __attribute__((ext_vector_type(8))) __bf16 bf16x8;
typedef __attribute__((ext_vector_type(4))) float f32x4;
typedef __attribute__((ext_vector_type(4))) unsigned int u32x4;

#define OUT_DIM 4096
#define IN_DIM  4096
#define M_DIM   8192

// ---------- Pass 1: cast x f32 -> bf16, accumulate per-row sums ----------
__global__ __launch_bounds__(256) void cvt_x_kernel(
    const float* __restrict__ x, bf16* __restrict__ xb, float* __restrict__ rowsum)
{
  const long t = (long)blockIdx.x * 256 + threadIdx.x;
  const long i = t * 8;
  const f32x4 a = *(const f32x4*)(x + i);
  const f32x4 b = *(const f32x4*)(x + i + 4);
  union { bf16 h[8]; u32x4 u; } r;
#pragma unroll
  for (int q = 0; q < 4; ++q) { r.h[q] = (bf16)a[q]; r.h[4+q] = (bf16)b[q]; }
  *(u32x4*)(xb + i) = r.u;
  float p = 0.f;
#pragma unroll
  for (int q = 0; q < 8; ++q) p += (float)r.h[q];
#pragma unroll
  for (int off = 32; off > 0; off >>= 1) p += __shfl_down(p, off);
  if ((threadIdx.x & 63) == 0) atomicAdd(&rowsum[(long)(t >> 9)], p);
}

// ---------- Pass 2: repack int32 -> bytes ----------
__global__ __launch_bounds__(256) void repack_w_kernel(
    const int* __restrict__ wp, unsigned int* __restrict__ wb)
{
  const long t = (long)blockIdx.x * 256 + threadIdx.x;   // 524,288 threads
  const long e = t * 16;
  u32x4 r;
#pragma unroll
  for (int q = 0; q < 4; ++q) {
    const int4 p = *(const int4*)(wp + e + q * 4);
    r[q] = (unsigned)(p.x & 255) | ((unsigned)(p.y & 255) << 8) |
           ((unsigned)(p.z & 255) << 16) | ((unsigned)(p.w & 255) << 24);
  }
  *(u32x4*)(wb + t * 4) = r;
}

// ---------- Pass 3: 256x128 fused-dequant GEMM, 4 waves, 2 blocks/CU ----------
// LDS: smA[2 buf][2 ks][256][32] bf16 (64 KB, st_16x32 swizzled);
//      smB[2 buf][2 ks][512] u32 (8 KB) packed nibbles:
//      word W: wc=W>>8, l15=(W>>4)&15, q=(W>>2)&3, f=W&3 -> col wc*64+f*16+l15,
//      K-half bytes q*4..q*4+3.  Lane reads ONE b128 at ((wc*16+l15)*4+q)*16.
// Phase (2/K-tile): vmcnt(6) -> barrier -> 1 b128 B-read + 8 b128 A-reads ->
// stage next group (4x16B A + 2x4B B) -> magic-bit dequant -> 32 MFMA.
__global__ __launch_bounds__(256, 2) void gemm_bt_bias_kernel(
    const bf16* __restrict__ A, const unsigned char* __restrict__ WP,
    const float* __restrict__ scale, const float* __restrict__ zp,
    const float* __restrict__ bias, const float* __restrict__ rowsum,
    float* __restrict__ C)
{
  const int N = OUT_DIM, K = IN_DIM;
  const int NT = IN_DIM / 64;            // 64 K-tiles

  __shared__ bf16 smA[2][2][256][32];    // 64 KiB
  __shared__ unsigned int smB[2][2][512];// 8 KiB

  // T1: XCD-aware bijective swizzle (1024 blocks, % 8 == 0)
  const int bid = blockIdx.x;
  const int swz = (bid & 7) * 128 + (bid >> 3);
  const int bm = swz >> 5;               // 32 M-tiles (256 rows)
  const int bn = swz & 31;               // 32 N-tiles (128 cols)

  const int tid  = threadIdx.x;
  const int lane = tid & 63;
  const int wave = tid >> 6;             // 0..3
  const int wr = wave >> 1;              // 0..1 -> 128-row strip
  const int wc = wave & 1;               // 0..1 -> 64-col strip

  const long row0 = (long)bm * 256;
  const long col0 = (long)bn * 128;

  // --- A staging sources: 4 chunks of 4 KB, pre-swizzled global src ---
  const bf16* aP0; const bf16* aP1; const bf16* aP2; const bf16* aP3;
  {
#define MKA(c, P) { const int L = (c)*4096 + tid*16;                            \
      const int Lw = L ^ (((L >> 9) & 1) << 5);                                 \
      P = A + (row0 + (Lw >> 6)) * (long)K + ((Lw & 63) >> 1); }
    MKA(0, aP0) MKA(1, aP1) MKA(2, aP2) MKA(3, aP3)
#undef MKA
  }
  const int LA = tid * 16;               // byte offset within each 4 KB chunk stride

  // --- B staging sources: words W0=tid, W1=256+tid ---
  const int W0 = tid, W1 = 256 + tid;
  const long bn0 = col0 + (W0 >> 8) * 64 + (W0 & 3) * 16 + ((W0 >> 4) & 15);
  const long bn1 = col0 + (W1 >> 8) * 64 + (W1 & 3) * 16 + ((W1 >> 4) & 15);
  const unsigned char* w0 = WP + bn0 * 2048L + ((W0 >> 2) & 3) * 4;
  const unsigned char* w1 = WP + bn1 * 2048L + ((W1 >> 2) & 3) * 4;

#define STAGE_G(BUF, KS, KOFF) do {                                             \
    char* Ah = (char*)&smA[BUF][KS][0][0];                                      \
    char* Bh = (char*)&smB[BUF][KS][0];                                         \
    __builtin_amdgcn_global_load_lds(                                           \
        (const __attribute__((address_space(1))) void*)(aP0 + (KOFF)),          \
        (__attribute__((address_space(3))) void*)(Ah + LA), 16, 0, 0);          \
    __builtin_amdgcn_global_load_lds(                                           \
        (const __attribute__((address_space(1))) void*)(aP1 + (KOFF)),          \
        (__attribute__((address_space(3))) void*)(Ah + 4096 + LA), 16, 0, 0);   \
    __builtin_amdgcn_global_load_lds(                                           \
        (const __attribute__((address_space(1))) void*)(aP2 + (KOFF)),          \
        (__attribute__((address_space(3))) void*)(Ah + 8192 + LA), 16, 0, 0);   \
    __builtin_amdgcn_global_load_lds(                                           \
        (const __attribute__((address_space(1))) void*)(aP3 + (KOFF)),          \
        (__attribute__((address_space(3))) void*)(Ah + 12288 + LA), 16, 0, 0);  \
    __builtin_amdgcn_global_load_lds(                                           \
        (const __attribute__((address_space(1))) void*)(w0 + ((KOFF) >> 1)),    \
        (__attribute__((address_space(3))) void*)(Bh + tid * 4), 4, 0, 0);      \
    __builtin_amdgcn_global_load_lds(                                           \
        (const __attribute__((address_space(1))) void*)(w1 + ((KOFF) >> 1)),    \
        (__attribute__((address_space(3))) void*)(Bh + 1024 + tid * 4), 4, 0, 0);\
  } while (0)

  // --- read-side per-lane constants ---
  const int lane15 = lane & 15;
  const int rb  = (lane15 * 64 + ((lane >> 4) << 4)) ^ ((lane & 8) << 2);  // A swizzled
  const int wrB = wr * 8192;                                               // 128-row strip
  const int rBb = ((wc * 16 + lane15) * 4 + (lane >> 4)) * 16;             // B b128 byte addr

  // per-lane epilogue constants for the 4 col-frags
  float sv16[4], ev[4];
#pragma unroll
  for (int f = 0; f < 4; ++f) {
    const int n = (int)col0 + wc * 64 + f * 16 + lane15;
    const float s = scale[n];
    sv16[f] = 16.f * s;
    ev[f]   = s * (16.f + zp[n]);
  }

  f32x4 acc[8][4] = {};

#define PHASE(BUF, KS, STAGE_STMT, VM_STMT) do {                                \
    VM_STMT;                                                                    \
    __builtin_amdgcn_s_barrier();                                               \
    asm volatile("" ::: "memory");  /* keep LDS reads below the barrier */      \
    const char* Ab = (const char*)&smA[BUF][KS][0][0];                          \
    const char* Bp = (const char*)&smB[BUF][KS][0];                             \
    const u32x4 pkv = *(const u32x4*)(Bp + rBb);                                \
    bf16x8 fa[8];                                                               \
    _Pragma("unroll")                                                           \
    for (int f = 0; f < 8; ++f) fa[f] = *(const bf16x8*)(Ab + wrB + f * 1024 + rb); \
    STAGE_STMT;                                                                 \
    bf16x8 fb[4];                                                               \
    _Pragma("unroll")                                                           \
    for (int f = 0; f < 4; ++f) {                                               \
      union { unsigned int u[4]; bf16x8 h; } bb;                                \
      const unsigned int pk = pkv[f];                                           \
      _Pragma("unroll")                                                         \
      for (int g = 0; g < 4; ++g) {                                             \
        const unsigned int tt = pk >> (8 * g);                                  \
        bb.u[g] = 0x3F803F80u | ((tt & 15u) << 3) | ((tt & 0xF0u) << 15);       \
      }                                                                         \
      fb[f] = bb.h;                                                             \
    }                                                                           \
    __builtin_amdgcn_s_setprio(1);                                              \
    _Pragma("unroll")                                                           \
    for (int i = 0; i < 8; ++i)                                                 \
      _Pragma("unroll")                                                         \
      for (int j = 0; j < 4; ++j)                                               \
        acc[i][j] = __builtin_amdgcn_mfma_f32_16x16x32_bf16(fa[i], fb[j], acc[i][j], 0, 0, 0); \
    __builtin_amdgcn_s_setprio(0);                                              \
  } while (0)

  // Prologue: tile 0, both ks groups (12 ops in flight)
  STAGE_G(0, 0, 0);
  STAGE_G(0, 1, 32);

  for (int T = 0; T < NT; ++T) {
    const int buf = T & 1;
    const int nbuf = buf ^ 1;
    const int nko = (T + 1) * 64;
    const bool st = (T + 1 < NT);

    PHASE(buf, 0,
          { if (st) STAGE_G(nbuf, 0, nko); },
          { asm volatile("s_waitcnt vmcnt(6)" ::: "memory"); });
    PHASE(buf, 1,
          { if (st) STAGE_G(nbuf, 1, nko + 32); },
          { if (T == NT - 1) asm volatile("s_waitcnt vmcnt(0)" ::: "memory");
            else             asm volatile("s_waitcnt vmcnt(6)" ::: "memory"); });
  }

  // Epilogue: out = 16*s*acc - s*(16+zp)*rowsum + bias
  const long cr0 = row0 + wr * 128 + ((lane >> 4) << 2);
  const long cc0 = col0 + wc * 64 + lane15;
#pragma unroll
  for (int j = 0; j < 4; ++j) {
    const long gc = cc0 + j * 16;
    const float bv = bias[gc];
    const float sj = sv16[j], e = ev[j];
#pragma unroll
    for (int mf = 0; mf < 8; ++mf) {
      const long gr = cr0 + mf * 16;
      float* cp = C + gr * (long)N + gc;
#pragma unroll
      for (int r = 0; r < 4; ++r)
        cp[(long)r * N] = acc[mf][j][r] * sj - e * rowsum[gr + r] + bv;
    }
  }
#undef PHASE
#undef STAGE_G
}

extern "C" void kernel_launch(void* const* d_in, const int* in_sizes, int n_in,
                              void* d_out, int out_size, void* d_ws, size_t ws_size,
                              hipStream_t stream)
{
  const float* x     = (const float*)d_in[0];
  const int*   wp    = (const int*)d_in[1];     // int32 per packed byte
  const float* scale = (const float*)d_in[2];
  const float* zp    = (const float*)d_in[3];
  const float* bias  = (const float*)d_in[4];
  float* out = (float*)d_out;

  bf16* Xb = (bf16*)d_ws;                                         // 67,108,864 B
  unsigned int* Wb = (unsigned int*)((char*)d_ws + 67108864);     //  8,388,608 B
  float* Rs = (float*)((char*)d_ws + 67108864 + 8388608);         //     32,768 B

  hipMemsetAsync(Rs, 0, M_DIM * sizeof(float), stream);
  cvt_x_kernel<<<(M_DIM * (long)IN_DIM / 8) / 256, 256, 0, stream>>>(x, Xb, Rs);
  repack_w_kernel<<<(OUT_DIM * (long)IN_DIM / 2 / 16) / 256, 256, 0, stream>>>(wp, Wb);
  // grid = (8192/256)*(4096/128) = 32*32 = 1024 blocks, 256 threads
  gemm_bt_bias_kernel<<<1024, 256, 0, stream>>>(
      Xb, (const unsigned char*)Wb, scale, zp, bias, Rs, out);
}